// Round 2
// baseline (1365.709 us; speedup 1.0000x reference)
//
#include <hip/hip_runtime.h>
#include <cstdint>
#include <cstddef>

#define SEQ 32768
#define DIM 1024
#define HID 128
#define KMAXV 103   // int(0.1*1024)+1

// ---------------------------------------------------------------------------
// Kernel A: per-block partial column sums of x (f64, deterministic order).
// 256 blocks x 256 threads; block b handles rows [b*128, b*128+128).
// ---------------------------------------------------------------------------
__global__ __launch_bounds__(256) void pool_partial(const float* __restrict__ x,
                                                    double* __restrict__ part) {
    const int b = blockIdx.x;
    const int t = threadIdx.x;
    const int r0 = b * 128;
    double s0 = 0.0, s1 = 0.0, s2 = 0.0, s3 = 0.0;
    for (int r = 0; r < 128; ++r) {
        const float* row = x + (size_t)(r0 + r) * DIM;
        s0 += (double)row[t];
        s1 += (double)row[t + 256];
        s2 += (double)row[t + 512];
        s3 += (double)row[t + 768];
    }
    double* p = part + (size_t)b * DIM;
    p[t] = s0; p[t + 256] = s1; p[t + 512] = s2; p[t + 768] = s3;
}

// ---------------------------------------------------------------------------
// Kernel B: finish pooling, complexity net (exact erf GELU, sigmoid), k.
// Single block of 1024 threads. f64 (true value; k is far from a truncation
// boundary so precision here cannot change k).
// ---------------------------------------------------------------------------
__global__ __launch_bounds__(1024) void tiny_net(const double* __restrict__ part,
                                                 const float* __restrict__ w1,
                                                 const float* __restrict__ b1,
                                                 const float* __restrict__ w2,
                                                 const float* __restrict__ b2,
                                                 float* __restrict__ out_scalars,
                                                 int* __restrict__ kout) {
    __shared__ double pooled[DIM];
    __shared__ double hidv[HID];
    const int t = threadIdx.x;

    double s = 0.0;
    for (int b = 0; b < 256; ++b) s += part[(size_t)b * DIM + t];
    pooled[t] = s / (double)SEQ;
    __syncthreads();

    if (t < HID) {
        double h = (double)b1[t];
        for (int d = 0; d < DIM; ++d) h += pooled[d] * (double)w1[d * HID + t];
        h = 0.5 * h * (1.0 + erf(h * 0.70710678118654752440));
        hidv[t] = h;
    }
    __syncthreads();

    if (t == 0) {
        double z = (double)b2[0];
        for (int j = 0; j < HID; ++j) z += hidv[j] * (double)w2[j];
        double c = 1.0 / (1.0 + exp(-z));
        double ar = 0.01 + 0.09 * c;
        int k = (int)(ar * (double)DIM);  // trunc
        if (k < 1) k = 1;
        if (k > KMAXV) k = KMAXV;
        out_scalars[0] = (float)c;
        out_scalars[1] = (float)ar;
        out_scalars[2] = (float)k;
        *kout = k;
    }
}

// ---------------------------------------------------------------------------
// Kernel C: importance GEMM replicating numpy/OpenBLAS f32 sgemm semantics:
// per output element, sequential-k FMA within K-panels {384,320,320}
// (OpenBLAS Zen/Haswell: Q=384, last two panels balanced), panel sums added
// in order: fl(fl(P1+P2)+P3). Then f32 epilogue exactly as the reference, and
// exact per-row dynamic-k threshold (tie-inclusive >=) via u32 radix search.
// Grid: SEQ/BM blocks of 512 threads. BM=16 rows per block.
// Thread t: columns c=(t&255)+256*j (j=0..3), rows rg*8..rg*8+7 (rg=t>>8).
// ---------------------------------------------------------------------------
#define BM 16
#define BK 64
#define CBLOCK 512

__global__ __launch_bounds__(CBLOCK) void gate_kernel(const float* __restrict__ x,
                                                      const float* __restrict__ wg,
                                                      const float* __restrict__ bg,
                                                      const float* __restrict__ rm,
                                                      const float* __restrict__ rv,
                                                      const int* __restrict__ kptr,
                                                      float* __restrict__ out) {
    __shared__ float xs[BM][BK];
    __shared__ float selbuf[8][DIM];

    const int t = threadIdx.x;
    const int c = t & 255;
    const int rg = t >> 8;           // 0 or 1
    const int row0 = blockIdx.x * BM;

    float dot[8][4];
#pragma unroll
    for (int m = 0; m < 8; ++m)
#pragma unroll
        for (int j = 0; j < 4; ++j) dot[m][j] = 0.0f;

    // K-panel boundaries in units of BK=64 tiles: {0..5}=384, {6..10}=320, {11..15}=320
    const int pstart[4] = {0, 6, 11, 16};

    for (int p = 0; p < 3; ++p) {
        float pacc[8][4];
#pragma unroll
        for (int m = 0; m < 8; ++m)
#pragma unroll
            for (int j = 0; j < 4; ++j) pacc[m][j] = 0.0f;

        for (int kt = pstart[p]; kt < pstart[p + 1]; ++kt) {
            __syncthreads();
            for (int i = t; i < BM * BK; i += CBLOCK) {
                const int r = i >> 6, cc = i & 63;
                xs[r][cc] = x[(size_t)(row0 + r) * DIM + kt * BK + cc];
            }
            __syncthreads();
#pragma unroll 4
            for (int kk = 0; kk < BK; ++kk) {
                const float* wrow = wg + (size_t)(kt * BK + kk) * DIM + c;
                const float w0  = wrow[0];
                const float w1v = wrow[256];
                const float w2v = wrow[512];
                const float w3v = wrow[768];
#pragma unroll
                for (int m = 0; m < 8; ++m) {
                    const float xv = xs[rg * 8 + m][kk];
                    pacc[m][0] = fmaf(xv, w0,  pacc[m][0]);
                    pacc[m][1] = fmaf(xv, w1v, pacc[m][1]);
                    pacc[m][2] = fmaf(xv, w2v, pacc[m][2]);
                    pacc[m][3] = fmaf(xv, w3v, pacc[m][3]);
                }
            }
        }
        // dot = ((P1 + P2) + P3) in f32, panel order (first add is exact 0+P1)
#pragma unroll
        for (int m = 0; m < 8; ++m)
#pragma unroll
            for (int j = 0; j < 4; ++j) dot[m][j] += pacc[m][j];
    }

    // f32 epilogue, op-for-op as numpy: abs(dot+bg); (v-rm)/(sqrt(rv)+1e-6f)
    float nbg[4], nrm[4], nden[4];
#pragma unroll
    for (int j = 0; j < 4; ++j) {
        const int col = c + 256 * j;
        nbg[j] = bg[col];
        nrm[j] = rm[col];
        nden[j] = sqrtf(rv[col]) + 1e-6f;
    }
    float imp[8][4];
#pragma unroll
    for (int m = 0; m < 8; ++m)
#pragma unroll
        for (int j = 0; j < 4; ++j) {
            const float v = fabsf(dot[m][j] + nbg[j]);
            imp[m][j] = (v - nrm[j]) / nden[j];
        }

    int kval = *kptr;
    if (kval < 1) kval = 1;
    if (kval > DIM) kval = DIM;

    // two chunks of 8 rows; one wave per row does exact kth-largest selection
    for (int ch = 0; ch < 2; ++ch) {
        __syncthreads();
        if (rg == ch) {
#pragma unroll
            for (int m = 0; m < 8; ++m)
#pragma unroll
                for (int j = 0; j < 4; ++j)
                    selbuf[m][c + 256 * j] = imp[m][j];
        }
        __syncthreads();

        const int w = t >> 6;    // wave id 0..7 -> row within chunk
        const int l = t & 63;    // lane
        const int srow = row0 + ch * 8 + w;

        // monotonic u32 keys for descending f32 order
        unsigned keys[16];
#pragma unroll
        for (int j = 0; j < 16; ++j) {
            const unsigned u = __float_as_uint(selbuf[w][l + 64 * j]);
            keys[j] = (u & 0x80000000u) ? ~u : (u | 0x80000000u);
        }

        // bitwise search for the kth-largest key: largest T with count(>=T) >= k
        unsigned pref = 0u;
        for (int b = 31; b >= 0; --b) {
            const unsigned tt = pref | (1u << b);
            int cnt = 0;
#pragma unroll
            for (int j = 0; j < 16; ++j) cnt += (keys[j] >= tt) ? 1 : 0;
#pragma unroll
            for (int off = 32; off >= 1; off >>= 1) cnt += __shfl_xor(cnt, off, 64);
            if (cnt >= kval) pref = tt;
        }

        // mask = importance >= kth  (tie-inclusive, matches reference)
#pragma unroll
        for (int j = 0; j < 16; ++j) {
            const int col = l + 64 * j;
            const float xv = x[(size_t)srow * DIM + col];
            out[(size_t)srow * DIM + col] = (keys[j] >= pref) ? xv : 0.0f;
        }
    }
}

// ---------------------------------------------------------------------------
extern "C" void kernel_launch(void* const* d_in, const int* in_sizes, int n_in,
                              void* d_out, int out_size, void* d_ws, size_t ws_size,
                              hipStream_t stream) {
    const float* x  = (const float*)d_in[0];
    const float* w1 = (const float*)d_in[1];
    const float* b1 = (const float*)d_in[2];
    const float* w2 = (const float*)d_in[3];
    const float* b2 = (const float*)d_in[4];
    const float* wg = (const float*)d_in[5];
    const float* bg = (const float*)d_in[6];
    const float* rm = (const float*)d_in[7];
    const float* rv = (const float*)d_in[8];
    float* out = (float*)d_out;

    double* part = (double*)d_ws;                                  // 256*1024 f64 = 2 MB
    int* kptr = (int*)((char*)d_ws + (size_t)256 * DIM * sizeof(double));

    pool_partial<<<256, 256, 0, stream>>>(x, part);
    tiny_net<<<1, 1024, 0, stream>>>(part, w1, b1, w2, b2,
                                     out + (size_t)SEQ * DIM, kptr);
    gate_kernel<<<SEQ / BM, CBLOCK, 0, stream>>>(x, wg, bg, rm, rv, kptr, out);
}

// Round 3
// 1153.438 us; speedup vs baseline: 1.1840x; 1.1840x over previous
//
#include <hip/hip_runtime.h>
#include <cstdint>
#include <cstddef>

#define SEQ 32768
#define DIM 1024
#define HID 128
#define KMAXV 103   // int(0.1*1024)+1

using f4 = __attribute__((ext_vector_type(4))) float;

// ---------------------------------------------------------------------------
// Kernel A: per-block partial column sums of x (f64, deterministic order).
// ---------------------------------------------------------------------------
__global__ __launch_bounds__(256) void pool_partial(const float* __restrict__ x,
                                                    double* __restrict__ part) {
    const int b = blockIdx.x;
    const int t = threadIdx.x;
    const int r0 = b * 128;
    double s0 = 0.0, s1 = 0.0, s2 = 0.0, s3 = 0.0;
    for (int r = 0; r < 128; ++r) {
        const float* row = x + (size_t)(r0 + r) * DIM;
        s0 += (double)row[t];
        s1 += (double)row[t + 256];
        s2 += (double)row[t + 512];
        s3 += (double)row[t + 768];
    }
    double* p = part + (size_t)b * DIM;
    p[t] = s0; p[t + 256] = s1; p[t + 512] = s2; p[t + 768] = s3;
}

// ---------------------------------------------------------------------------
// Kernel B: finish pooling, complexity net (exact erf GELU, sigmoid), k.
// ---------------------------------------------------------------------------
__global__ __launch_bounds__(1024) void tiny_net(const double* __restrict__ part,
                                                 const float* __restrict__ w1,
                                                 const float* __restrict__ b1,
                                                 const float* __restrict__ w2,
                                                 const float* __restrict__ b2,
                                                 float* __restrict__ out_scalars,
                                                 int* __restrict__ kout) {
    __shared__ double pooled[DIM];
    __shared__ double hidv[HID];
    const int t = threadIdx.x;

    double s = 0.0;
    for (int b = 0; b < 256; ++b) s += part[(size_t)b * DIM + t];
    pooled[t] = s / (double)SEQ;
    __syncthreads();

    if (t < HID) {
        double h = (double)b1[t];
        for (int d = 0; d < DIM; ++d) h += pooled[d] * (double)w1[d * HID + t];
        h = 0.5 * h * (1.0 + erf(h * 0.70710678118654752440));
        hidv[t] = h;
    }
    __syncthreads();

    if (t == 0) {
        double z = (double)b2[0];
        for (int j = 0; j < HID; ++j) z += hidv[j] * (double)w2[j];
        double c = 1.0 / (1.0 + exp(-z));
        double ar = 0.01 + 0.09 * c;
        int k = (int)(ar * (double)DIM);  // trunc
        if (k < 1) k = 1;
        if (k > KMAXV) k = KMAXV;
        out_scalars[0] = (float)c;
        out_scalars[1] = (float)ar;
        out_scalars[2] = (float)k;
        *kout = k;
    }
}

// ---------------------------------------------------------------------------
// Kernel C: importance GEMM with numpy/OpenBLAS f32 semantics (sequential-k
// FMA within panels {384,320,320}, panels summed in order) — NUMERICS FROZEN,
// bit-identical per-element order to the round-2 passing kernel.
// Structure: 512 threads = 2 row-groups x 256 col-threads; thread owns
// 8 rows x 4 CONTIGUOUS cols (dwordx4 wg loads). Full 16x1024 x-tile staged
// to LDS once (no barriers in K-loop), x read via broadcast ds_read_b128.
// Then exact per-row dynamic-k threshold (tie-inclusive >=) via u32 radix
// search, float4 coalesced output.
// ---------------------------------------------------------------------------
#define BM 16
#define CBLOCK 512

__global__ __launch_bounds__(CBLOCK, 4) void gate_kernel(const float* __restrict__ x,
                                                         const float* __restrict__ wg,
                                                         const float* __restrict__ bg,
                                                         const float* __restrict__ rm,
                                                         const float* __restrict__ rv,
                                                         const int* __restrict__ kptr,
                                                         float* __restrict__ out) {
    __shared__ float xs[BM][DIM];                 // 64 KB; selbuf aliases rows 0..7 after GEMM
    float (*selbuf)[DIM] = (float (*)[DIM])xs;

    const int t = threadIdx.x;
    const int c4 = (t & 255) << 2;   // 4 contiguous columns c4..c4+3
    const int rg = t >> 8;           // 0 or 1 -> rows rg*8..rg*8+7
    const int row0 = blockIdx.x * BM;

    // stage full x-tile (coalesced float4)
    {
        const f4* xg = (const f4*)(x + (size_t)row0 * DIM);
        f4* xl = (f4*)xs;
        for (int i = t; i < BM * (DIM / 4); i += CBLOCK) xl[i] = xg[i];
    }
    __syncthreads();

    float dot[8][4];
#pragma unroll
    for (int m = 0; m < 8; ++m)
#pragma unroll
        for (int j = 0; j < 4; ++j) dot[m][j] = 0.0f;

    const int pb[4] = {0, 384, 704, 1024};       // OpenBLAS K-panels
    const float* xrow = &xs[rg * 8][0];
    const float* wbase = wg + c4;

    for (int p = 0; p < 3; ++p) {
        float pacc[8][4];
#pragma unroll
        for (int m = 0; m < 8; ++m)
#pragma unroll
            for (int j = 0; j < 4; ++j) pacc[m][j] = 0.0f;

        for (int kk0 = pb[p]; kk0 < pb[p + 1]; kk0 += 4) {
            const f4 wq0 = *(const f4*)(wbase + (size_t)(kk0 + 0) * DIM);
            const f4 wq1 = *(const f4*)(wbase + (size_t)(kk0 + 1) * DIM);
            const f4 wq2 = *(const f4*)(wbase + (size_t)(kk0 + 2) * DIM);
            const f4 wq3 = *(const f4*)(wbase + (size_t)(kk0 + 3) * DIM);
#pragma unroll
            for (int m = 0; m < 8; ++m) {
                const f4 xv = *(const f4*)(xrow + m * DIM + kk0);
#pragma unroll
                for (int j = 0; j < 4; ++j) {
                    float a = pacc[m][j];
                    a = fmaf(xv[0], wq0[j], a);   // k = kk0
                    a = fmaf(xv[1], wq1[j], a);   // k = kk0+1
                    a = fmaf(xv[2], wq2[j], a);   // k = kk0+2
                    a = fmaf(xv[3], wq3[j], a);   // k = kk0+3
                    pacc[m][j] = a;
                }
            }
        }
#pragma unroll
        for (int m = 0; m < 8; ++m)
#pragma unroll
            for (int j = 0; j < 4; ++j) dot[m][j] += pacc[m][j];
    }

    // f32 epilogue, op-for-op as numpy
    const f4 vbg = *(const f4*)(bg + c4);
    const f4 vrm = *(const f4*)(rm + c4);
    const f4 vrv = *(const f4*)(rv + c4);
    f4 vden;
#pragma unroll
    for (int j = 0; j < 4; ++j) vden[j] = sqrtf(vrv[j]) + 1e-6f;

    f4 imp[8];
#pragma unroll
    for (int m = 0; m < 8; ++m)
#pragma unroll
        for (int j = 0; j < 4; ++j) {
            const float v = fabsf(dot[m][j] + vbg[j]);
            imp[m][j] = (v - vrm[j]) / vden[j];
        }

    int kval = *kptr;
    if (kval < 1) kval = 1;
    if (kval > DIM) kval = DIM;

    // two chunks of 8 rows; one wave per row does exact kth-largest selection
    for (int ch = 0; ch < 2; ++ch) {
        __syncthreads();
        if (rg == ch) {
#pragma unroll
            for (int m = 0; m < 8; ++m)
                *(f4*)(&selbuf[m][c4]) = imp[m];
        }
        __syncthreads();

        const int w = t >> 6;    // wave id 0..7 -> row within chunk
        const int l = t & 63;    // lane
        const size_t srow = (size_t)(row0 + ch * 8 + w);

        // monotonic u32 keys for descending f32 order; lane l owns cols 4l+256j+i
        unsigned keys[16];
#pragma unroll
        for (int j = 0; j < 4; ++j) {
            const f4 v = *(const f4*)(&selbuf[w][4 * l + 256 * j]);
#pragma unroll
            for (int i = 0; i < 4; ++i) {
                const unsigned u = __float_as_uint(v[i]);
                keys[j * 4 + i] = (u & 0x80000000u) ? ~u : (u | 0x80000000u);
            }
        }

        // bitwise search for the kth-largest key: largest T with count(>=T) >= k
        unsigned pref = 0u;
        for (int b = 31; b >= 0; --b) {
            const unsigned tt = pref | (1u << b);
            int cnt = 0;
#pragma unroll
            for (int j = 0; j < 16; ++j) cnt += (keys[j] >= tt) ? 1 : 0;
#pragma unroll
            for (int off = 32; off >= 1; off >>= 1) cnt += __shfl_xor(cnt, off, 64);
            if (cnt >= kval) pref = tt;
        }

        // mask = importance >= kth (tie-inclusive); coalesced float4 out
        const float* xr = x + srow * DIM;
        float* orow = out + srow * DIM;
#pragma unroll
        for (int j = 0; j < 4; ++j) {
            const f4 xv = *(const f4*)(xr + 4 * l + 256 * j);
            f4 o;
#pragma unroll
            for (int i = 0; i < 4; ++i) o[i] = (keys[j * 4 + i] >= pref) ? xv[i] : 0.0f;
            *(f4*)(orow + 4 * l + 256 * j) = o;
        }
    }
}

// ---------------------------------------------------------------------------
extern "C" void kernel_launch(void* const* d_in, const int* in_sizes, int n_in,
                              void* d_out, int out_size, void* d_ws, size_t ws_size,
                              hipStream_t stream) {
    const float* x  = (const float*)d_in[0];
    const float* w1 = (const float*)d_in[1];
    const float* b1 = (const float*)d_in[2];
    const float* w2 = (const float*)d_in[3];
    const float* b2 = (const float*)d_in[4];
    const float* wg = (const float*)d_in[5];
    const float* bg = (const float*)d_in[6];
    const float* rm = (const float*)d_in[7];
    const float* rv = (const float*)d_in[8];
    float* out = (float*)d_out;

    double* part = (double*)d_ws;                                  // 256*1024 f64 = 2 MB
    int* kptr = (int*)((char*)d_ws + (size_t)256 * DIM * sizeof(double));

    pool_partial<<<256, 256, 0, stream>>>(x, part);
    tiny_net<<<1, 1024, 0, stream>>>(part, w1, b1, w2, b2,
                                     out + (size_t)SEQ * DIM, kptr);
    gate_kernel<<<SEQ / BM, CBLOCK, 0, stream>>>(x, wg, bg, rm, rv, kptr, out);
}